// Round 4
// baseline (302.359 us; speedup 1.0000x reference)
//
#include <hip/hip_runtime.h>
#include <hip/hip_bf16.h>
#include <stdint.h>

// CapsuleLayer dynamic routing, MI355X (gfx950).
// B=64, I=2048, P=16, J=32, D=16, ROUTINGS=3.
// Round 4: same structure as round 3, but route inner loop in verifiable C++:
// __builtin_amdgcn_fdot2 (v_dot2_f32_f16) for logits, fmaf((float)h,c,acc)
// (compiler folds to v_fma_mix_f32) for accumulation. No hand VOP3P asm.

namespace {
constexpr int B_ = 64;
constexpr int I_ = 2048;
constexpr int P_ = 16;
constexpr int J_ = 32;
constexpr int D_ = 16;
constexpr int CI_ = 64;         // i-range per routing block
constexpr int ROWS_ = J_ * D_;  // 512 output rows per i

using half8 = __attribute__((ext_vector_type(8))) _Float16;
using h2    = __attribute__((ext_vector_type(2))) _Float16;
using f32x4 = __attribute__((ext_vector_type(4))) float;

__device__ __forceinline__ uint32_t pkh2(float a, float b) {
  union { h2 h; uint32_t u; } z;
  z.h[0] = (_Float16)a; z.h[1] = (_Float16)b;
  return z.u;
}
__device__ __forceinline__ h2 as_h2(uint32_t u) {
  union { uint32_t uu; h2 h; } z; z.uu = u; return z.h;
}
__device__ __forceinline__ float dot2acc(h2 a, h2 b, float c) {
#if __has_builtin(__builtin_amdgcn_fdot2)
  return __builtin_amdgcn_fdot2(a, b, c, false);
#else
  return fmaf((float)a[0], (float)b[0], fmaf((float)a[1], (float)b[1], c));
#endif
}

// ---------------------------------------------------------------------------
// K0: u_hat[b,i,row] = sum_p x[b,i,p] * W[i,row,p], stored fp16 as [b][i][row].
// One block per i; 4 waves. MFMA 16x16x32 f16 (k 16..31 zero-padded), operands
// swapped so D's M-dim = rowout (consecutive per lane-reg) and N-dim = b:
// A = W_i chunk [16 rowout x k=p], B = x_i^T [k=p x 16 b].
// Correctness: round 2 validated this exact (A-placement, B-placement, C/D
// store) triple with random data; swapping which tensor uses which placement
// is data-independent. D mapping: col(lane&15)=b-in-tile, row(4*(lane>>4)+reg)
// = rowout-in-tile -> 4 consecutive rowout per lane -> one 8B packed store.
// ---------------------------------------------------------------------------
__global__ __launch_bounds__(256) void k_uhat(const float* __restrict__ x,
                                              const float* __restrict__ W,
                                              uint16_t* __restrict__ uhat) {
  const int i = blockIdx.x;
  const int t = threadIdx.x;
  const int w = t >> 6;   // wave 0..3
  const int l = t & 63;
  const int g = l >> 4;   // 16-lane group
  const int r16 = l & 15;

  // B-frags: x^T tiles bm=0..3. Lane holds B[k=8g+e, col=b=16bm+r16]; k>=16 -> 0.
  half8 bfr[4];
#pragma unroll
  for (int bm = 0; bm < 4; ++bm) {
    half8 f;
#pragma unroll
    for (int e = 0; e < 8; ++e) f[e] = (_Float16)0.f;
    if (g < 2) {
      const float* bp = x + (size_t)(16 * bm + r16) * (I_ * P_) + (size_t)i * P_ + 8 * g;
      const float4 u0 = *reinterpret_cast<const float4*>(bp);
      const float4 u1 = *reinterpret_cast<const float4*>(bp + 4);
      f[0] = (_Float16)u0.x; f[1] = (_Float16)u0.y; f[2] = (_Float16)u0.z; f[3] = (_Float16)u0.w;
      f[4] = (_Float16)u1.x; f[5] = (_Float16)u1.y; f[6] = (_Float16)u1.z; f[7] = (_Float16)u1.w;
    }
    bfr[bm] = f;
  }

  const float* Wi = W + (size_t)i * (ROWS_ * P_);
  uint16_t* out_i = uhat + (size_t)i * ROWS_;

#pragma unroll
  for (int nn = 0; nn < 8; ++nn) {
    const int n = 8 * w + nn;  // rowout (M) tile
    // A-frag: lane holds A[row=r16 (rowout), k=8g+e]; k>=16 -> 0.
    half8 af;
#pragma unroll
    for (int e = 0; e < 8; ++e) af[e] = (_Float16)0.f;
    if (g < 2) {
      const float* ap = Wi + (size_t)(16 * n + r16) * P_ + 8 * g;
      const float4 u0 = *reinterpret_cast<const float4*>(ap);
      const float4 u1 = *reinterpret_cast<const float4*>(ap + 4);
      af[0] = (_Float16)u0.x; af[1] = (_Float16)u0.y; af[2] = (_Float16)u0.z; af[3] = (_Float16)u0.w;
      af[4] = (_Float16)u1.x; af[5] = (_Float16)u1.y; af[6] = (_Float16)u1.z; af[7] = (_Float16)u1.w;
    }

#pragma unroll
    for (int bm = 0; bm < 4; ++bm) {
      f32x4 acc;
      acc[0] = 0.f; acc[1] = 0.f; acc[2] = 0.f; acc[3] = 0.f;
      acc = __builtin_amdgcn_mfma_f32_16x16x32_f16(af, bfr[bm], acc, 0, 0, 0);
      const int b = 16 * bm + r16;
      const int ro = 16 * n + 4 * g;  // acc[r] -> rowout ro+r
      uint2 st;
      st.x = pkh2(acc[0], acc[1]);
      st.y = pkh2(acc[2], acc[3]);
      *reinterpret_cast<uint2*>(out_i + (size_t)b * (I_ * ROWS_) + ro) = st;
    }
  }
}

// ---------------------------------------------------------------------------
// squash(s_row) added into v[16]; s_row is 64B contiguous fp32.
// ---------------------------------------------------------------------------
__device__ __forceinline__ void load_squash_add(const float* __restrict__ p, float* v) {
  const float4* sp = reinterpret_cast<const float4*>(p);
  const float4 a0 = sp[0], a1 = sp[1], a2 = sp[2], a3 = sp[3];
  float n2 = 1e-7f;
  n2 += a0.x * a0.x + a0.y * a0.y + a0.z * a0.z + a0.w * a0.w;
  n2 += a1.x * a1.x + a1.y * a1.y + a1.z * a1.z + a1.w * a1.w;
  n2 += a2.x * a2.x + a2.y * a2.y + a2.z * a2.z + a2.w * a2.w;
  n2 += a3.x * a3.x + a3.y * a3.y + a3.z * a3.z + a3.w * a3.w;
  const float sc = n2 / ((1.f + n2) * sqrtf(n2));
  v[0] += sc * a0.x;  v[1] += sc * a0.y;  v[2] += sc * a0.z;  v[3] += sc * a0.w;
  v[4] += sc * a1.x;  v[5] += sc * a1.y;  v[6] += sc * a1.z;  v[7] += sc * a1.w;
  v[8] += sc * a2.x;  v[9] += sc * a2.y;  v[10] += sc * a2.z; v[11] += sc * a2.w;
  v[12] += sc * a3.x; v[13] += sc * a3.y; v[14] += sc * a3.z; v[15] += sc * a3.w;
}

// ---------------------------------------------------------------------------
// K_route<PASS>: one routing pass over fp16 u_hat.
//   PASS 0: c = 1/32 (softmax of zero logits).
//   PASS 1: vsum = squash(s0);  PASS 2: vsum = squash(s0)+squash(s1).
//   logit = dot(u, vsum) via fdot2; c = softmax_j (no max-sub: |logit| <~ 12,
//   exp safe in f32); acc += c*u via fmaf((float)h, c, acc) -> v_fma_mix_f32.
// grid = (I/CI, B) x 256. lane&31 = j; 32-wide shfl softmax; LDS cross-wave
// reduce; 512 f32 atomics per block.
// ---------------------------------------------------------------------------
template <int PASS>
__global__ __launch_bounds__(256) void k_route(const uint4* __restrict__ uhat,
                                               const float* __restrict__ s0,
                                               const float* __restrict__ s1,
                                               float* __restrict__ sout) {
  const int b = blockIdx.y;
  const int i0 = blockIdx.x * CI_;
  const int t = threadIdx.x;
  const int lane = t & 63;
  const int wave = t >> 6;    // 0..3
  const int sub = lane >> 5;  // i sub-stream
  const int j = lane & 31;

  h2 vh[8];
  if constexpr (PASS > 0) {
    float v[16];
#pragma unroll
    for (int d = 0; d < D_; ++d) v[d] = 0.f;
    load_squash_add(s0 + ((size_t)b * J_ + j) * D_, v);
    if constexpr (PASS == 2) load_squash_add(s1 + ((size_t)b * J_ + j) * D_, v);
#pragma unroll
    for (int q = 0; q < 8; ++q) {
      h2 hv;
      hv[0] = (_Float16)v[2 * q];
      hv[1] = (_Float16)v[2 * q + 1];
      vh[q] = hv;
    }
  }

  float acc[D_];
#pragma unroll
  for (int d = 0; d < D_; ++d) acc[d] = 0.f;

  const uint4* up = uhat + (((size_t)b * I_ + i0 + wave * 2 + sub) * J_ + j) * 2;
  const size_t step = (size_t)8 * J_ * 2;  // 8 i's per iteration (uint4 units)

#pragma unroll 2
  for (int it = 0; it < CI_ / 8; ++it, up += step) {
    const uint4 q0 = up[0], q1 = up[1];  // 16 fp16 = one (b,i,j,:) row
    const h2 u0 = as_h2(q0.x), u1 = as_h2(q0.y), u2 = as_h2(q0.z), u3 = as_h2(q0.w);
    const h2 u4 = as_h2(q1.x), u5 = as_h2(q1.y), u6 = as_h2(q1.z), u7 = as_h2(q1.w);
    float c;
    if constexpr (PASS == 0) {
      c = 1.0f;
    } else {
      float lg = 0.f;
      lg = dot2acc(u0, vh[0], lg); lg = dot2acc(u1, vh[1], lg);
      lg = dot2acc(u2, vh[2], lg); lg = dot2acc(u3, vh[3], lg);
      lg = dot2acc(u4, vh[4], lg); lg = dot2acc(u5, vh[5], lg);
      lg = dot2acc(u6, vh[6], lg); lg = dot2acc(u7, vh[7], lg);
      const float e = __expf(lg);
      float sm = e;
#pragma unroll
      for (int off = 16; off > 0; off >>= 1) sm += __shfl_xor(sm, off, 32);
      c = e * __builtin_amdgcn_rcpf(sm);
    }
    acc[0]  = fmaf((float)u0[0], c, acc[0]);  acc[1]  = fmaf((float)u0[1], c, acc[1]);
    acc[2]  = fmaf((float)u1[0], c, acc[2]);  acc[3]  = fmaf((float)u1[1], c, acc[3]);
    acc[4]  = fmaf((float)u2[0], c, acc[4]);  acc[5]  = fmaf((float)u2[1], c, acc[5]);
    acc[6]  = fmaf((float)u3[0], c, acc[6]);  acc[7]  = fmaf((float)u3[1], c, acc[7]);
    acc[8]  = fmaf((float)u4[0], c, acc[8]);  acc[9]  = fmaf((float)u4[1], c, acc[9]);
    acc[10] = fmaf((float)u5[0], c, acc[10]); acc[11] = fmaf((float)u5[1], c, acc[11]);
    acc[12] = fmaf((float)u6[0], c, acc[12]); acc[13] = fmaf((float)u6[1], c, acc[13]);
    acc[14] = fmaf((float)u7[0], c, acc[14]); acc[15] = fmaf((float)u7[1], c, acc[15]);
  }
  if constexpr (PASS == 0) {
#pragma unroll
    for (int d = 0; d < D_; ++d) acc[d] *= (1.0f / J_);
  }
  // combine the wave's two i-substreams (lane l <-> l^32, same j)
#pragma unroll
  for (int d = 0; d < D_; ++d) acc[d] += __shfl_xor(acc[d], 32, 64);

  __shared__ float sp[4][J_][D_ + 1];
  if (sub == 0) {
#pragma unroll
    for (int d = 0; d < D_; ++d) sp[wave][j][d] = acc[d];
  }
  __syncthreads();
  for (int k = t; k < J_ * D_; k += 256) {
    const int jj = k >> 4, dd = k & 15;
    atomicAdd(sout + (size_t)b * (J_ * D_) + k,
              sp[0][jj][dd] + sp[1][jj][dd] + sp[2][jj][dd] + sp[3][jj][dd]);
  }
}

// ---------------------------------------------------------------------------
// K_squash: out = squash(s2).
// ---------------------------------------------------------------------------
__global__ __launch_bounds__(256) void k_squash(const float* __restrict__ s,
                                                float* __restrict__ out) {
  const int r = blockIdx.x * 256 + threadIdx.x;  // row over B*J
  if (r >= B_ * J_) return;
  const float4* sp = reinterpret_cast<const float4*>(s + (size_t)r * D_);
  float4 a[4] = {sp[0], sp[1], sp[2], sp[3]};
  float n2 = 1e-7f;
#pragma unroll
  for (int c = 0; c < 4; ++c)
    n2 += a[c].x * a[c].x + a[c].y * a[c].y + a[c].z * a[c].z + a[c].w * a[c].w;
  const float sc = n2 / ((1.f + n2) * sqrtf(n2));
  float4* op = reinterpret_cast<float4*>(out + (size_t)r * D_);
#pragma unroll
  for (int c = 0; c < 4; ++c) {
    float4 v = a[c];
    v.x *= sc; v.y *= sc; v.z *= sc; v.w *= sc;
    op[c] = v;
  }
}

}  // namespace

extern "C" void kernel_launch(void* const* d_in, const int* in_sizes, int n_in,
                              void* d_out, int out_size, void* d_ws, size_t ws_size,
                              hipStream_t stream) {
  const float* x = (const float*)d_in[0];   // [B, I, P] fp32
  const float* W = (const float*)d_in[1];   // [I, J, D, P] fp32
  float* out = (float*)d_out;               // [B, J, D] fp32

  char* ws = (char*)d_ws;
  uint16_t* uhat = (uint16_t*)ws;                               // 128 MB fp16
  const size_t UHAT_BYTES = (size_t)B_ * I_ * ROWS_ * 2;
  float* s0 = (float*)(ws + UHAT_BYTES);
  float* s1 = s0 + B_ * J_ * D_;
  float* s2 = s1 + B_ * J_ * D_;

  hipMemsetAsync(s0, 0, (size_t)3 * B_ * J_ * D_ * sizeof(float), stream);

  k_uhat<<<I_, 256, 0, stream>>>(x, W, uhat);

  const dim3 rg(I_ / CI_, B_);
  k_route<0><<<rg, 256, 0, stream>>>((const uint4*)uhat, nullptr, nullptr, s0);
  k_route<1><<<rg, 256, 0, stream>>>((const uint4*)uhat, s0, nullptr, s1);
  k_route<2><<<rg, 256, 0, stream>>>((const uint4*)uhat, s0, s1, s2);
  k_squash<<<(B_ * J_ + 255) / 256, 256, 0, stream>>>(s2, out);
}

// Round 6
// 263.131 us; speedup vs baseline: 1.1491x; 1.1491x over previous
//
#include <hip/hip_runtime.h>
#include <hip/hip_bf16.h>
#include <stdint.h>

// CapsuleLayer dynamic routing, MI355X (gfx950).
// B=64, I=2048, P=16, J=32, D=16, ROUTINGS=3.
// Round 5 (resubmit; prior attempt hit GPU-acquisition timeout, never ran):
// u_hat transposed to [i][b][row] (block-owned 64KB store regions ->
// no partial-line write amplification); route writes per-block partials
// (no atomics); k_finish reduces partials + squash + vsum/out.

namespace {
constexpr int B_ = 64;
constexpr int I_ = 2048;
constexpr int P_ = 16;
constexpr int J_ = 32;
constexpr int D_ = 16;
constexpr int CI_ = 128;        // i-range per routing block
constexpr int NBLK_ = I_ / CI_; // 16 partial slabs per b
constexpr int ROWS_ = J_ * D_;  // 512 output rows per i

using half8 = __attribute__((ext_vector_type(8))) _Float16;
using h2    = __attribute__((ext_vector_type(2))) _Float16;
using f32x4 = __attribute__((ext_vector_type(4))) float;

__device__ __forceinline__ uint32_t pkh2(float a, float b) {
  union { h2 h; uint32_t u; } z;
  z.h[0] = (_Float16)a; z.h[1] = (_Float16)b;
  return z.u;
}
__device__ __forceinline__ h2 as_h2(uint32_t u) {
  union { uint32_t uu; h2 h; } z; z.uu = u; return z.h;
}
__device__ __forceinline__ float dot2acc(h2 a, h2 b, float c) {
#if __has_builtin(__builtin_amdgcn_fdot2)
  return __builtin_amdgcn_fdot2(a, b, c, false);
#else
  return fmaf((float)a[0], (float)b[0], fmaf((float)a[1], (float)b[1], c));
#endif
}

// ---------------------------------------------------------------------------
// K0: u_hat[i][b][row] = sum_p x[b,i,p] * W[i,row,p], fp16.
// One block per i -> block-owned 64KB contiguous output. MFMA 16x16x32 f16
// (k 16..31 zero-padded), operand placement identical to round 4 (validated):
// A = W_i chunk [M=16 rowout x K=p], B = x_i^T [K=p x N=16 b].
// D mapping: col(lane&15)=b-in-tile, row(4*(lane>>4)+reg)=rowout-in-tile ->
// lane stores 4 consecutive rowout at fixed b as one 8B packed store.
// Each 128B line ([b][ro 0..63]) is fully written by one wave in 4 nn-iters.
// ---------------------------------------------------------------------------
__global__ __launch_bounds__(256) void k_uhat(const float* __restrict__ x,
                                              const float* __restrict__ W,
                                              uint16_t* __restrict__ uhat) {
  const int i = blockIdx.x;
  const int t = threadIdx.x;
  const int w = t >> 6;   // wave 0..3
  const int l = t & 63;
  const int g = l >> 4;   // 16-lane group
  const int r16 = l & 15;

  // B-frags: x^T tiles bm=0..3. Lane holds B[k=8g+e, col=b=16bm+r16]; k>=16 -> 0.
  half8 bfr[4];
#pragma unroll
  for (int bm = 0; bm < 4; ++bm) {
    half8 f;
#pragma unroll
    for (int e = 0; e < 8; ++e) f[e] = (_Float16)0.f;
    if (g < 2) {
      const float* bp = x + (size_t)(16 * bm + r16) * (I_ * P_) + (size_t)i * P_ + 8 * g;
      const float4 u0 = *reinterpret_cast<const float4*>(bp);
      const float4 u1 = *reinterpret_cast<const float4*>(bp + 4);
      f[0] = (_Float16)u0.x; f[1] = (_Float16)u0.y; f[2] = (_Float16)u0.z; f[3] = (_Float16)u0.w;
      f[4] = (_Float16)u1.x; f[5] = (_Float16)u1.y; f[6] = (_Float16)u1.z; f[7] = (_Float16)u1.w;
    }
    bfr[bm] = f;
  }

  const float* Wi = W + (size_t)i * (ROWS_ * P_);
  uint16_t* out_i = uhat + (size_t)i * (B_ * ROWS_);  // 64KB region for this i

#pragma unroll
  for (int nn = 0; nn < 8; ++nn) {
    const int n = 8 * w + nn;  // rowout (M) tile
    half8 af;
#pragma unroll
    for (int e = 0; e < 8; ++e) af[e] = (_Float16)0.f;
    if (g < 2) {
      const float* ap = Wi + (size_t)(16 * n + r16) * P_ + 8 * g;
      const float4 u0 = *reinterpret_cast<const float4*>(ap);
      const float4 u1 = *reinterpret_cast<const float4*>(ap + 4);
      af[0] = (_Float16)u0.x; af[1] = (_Float16)u0.y; af[2] = (_Float16)u0.z; af[3] = (_Float16)u0.w;
      af[4] = (_Float16)u1.x; af[5] = (_Float16)u1.y; af[6] = (_Float16)u1.z; af[7] = (_Float16)u1.w;
    }

#pragma unroll
    for (int bm = 0; bm < 4; ++bm) {
      f32x4 acc;
      acc[0] = 0.f; acc[1] = 0.f; acc[2] = 0.f; acc[3] = 0.f;
      acc = __builtin_amdgcn_mfma_f32_16x16x32_f16(af, bfr[bm], acc, 0, 0, 0);
      const int b = 16 * bm + r16;
      const int ro = 16 * n + 4 * g;  // acc[r] -> rowout ro+r
      uint2 st;
      st.x = pkh2(acc[0], acc[1]);
      st.y = pkh2(acc[2], acc[3]);
      *reinterpret_cast<uint2*>(out_i + (size_t)b * ROWS_ + ro) = st;
    }
  }
}

// ---------------------------------------------------------------------------
// K_route<UNIFORM>: one routing pass over fp16 u_hat[i][b][row].
//   UNIFORM: c = 1/32 (pass 0). Else logit = dot(u, vsum) (fdot2), softmax_j
//   (no max-sub; |logit| small), acc += c*u (mix-FMA via fmaf((float)h,...)).
// grid = (I/CI, B) x 256. lane&31 = j. Output: block partial sums to
// part[b][blk][512] with PLAIN stores (no atomics).
// ---------------------------------------------------------------------------
template <bool UNIFORM>
__global__ __launch_bounds__(256) void k_route(const uint4* __restrict__ uhat,
                                               const float* __restrict__ vsum,
                                               float* __restrict__ part) {
  const int b = blockIdx.y;
  const int i0 = blockIdx.x * CI_;
  const int t = threadIdx.x;
  const int lane = t & 63;
  const int wave = t >> 6;    // 0..3
  const int sub = lane >> 5;  // i sub-stream
  const int j = lane & 31;

  h2 vh[8];
  if constexpr (!UNIFORM) {
    const float4* vp = reinterpret_cast<const float4*>(vsum + ((size_t)b * J_ + j) * D_);
#pragma unroll
    for (int q = 0; q < 4; ++q) {
      const float4 v = vp[q];
      h2 a, bb;
      a[0] = (_Float16)v.x; a[1] = (_Float16)v.y;
      bb[0] = (_Float16)v.z; bb[1] = (_Float16)v.w;
      vh[2 * q] = a; vh[2 * q + 1] = bb;
    }
  }

  float acc[D_];
#pragma unroll
  for (int d = 0; d < D_; ++d) acc[d] = 0.f;

  // uint4 units: row (i,b,j) starts at ((i*B + b)*ROWS + j*16)/8
  const uint4* up = uhat + ((size_t)(i0 + wave * 2 + sub) * B_ + b) * (ROWS_ / 8) + j * 2;
  const size_t step = (size_t)8 * B_ * (ROWS_ / 8);  // 8 i's per iteration

#pragma unroll 2
  for (int it = 0; it < CI_ / 8; ++it, up += step) {
    const uint4 q0 = up[0], q1 = up[1];  // 16 fp16 = one (i,b,j,:) row
    const h2 u0 = as_h2(q0.x), u1 = as_h2(q0.y), u2 = as_h2(q0.z), u3 = as_h2(q0.w);
    const h2 u4 = as_h2(q1.x), u5 = as_h2(q1.y), u6 = as_h2(q1.z), u7 = as_h2(q1.w);
    float c;
    if constexpr (UNIFORM) {
      c = 1.0f;
    } else {
      float lg = 0.f;
      lg = dot2acc(u0, vh[0], lg); lg = dot2acc(u1, vh[1], lg);
      lg = dot2acc(u2, vh[2], lg); lg = dot2acc(u3, vh[3], lg);
      lg = dot2acc(u4, vh[4], lg); lg = dot2acc(u5, vh[5], lg);
      lg = dot2acc(u6, vh[6], lg); lg = dot2acc(u7, vh[7], lg);
      const float e = __expf(lg);
      float sm = e;
#pragma unroll
      for (int off = 16; off > 0; off >>= 1) sm += __shfl_xor(sm, off, 32);
      c = e * __builtin_amdgcn_rcpf(sm);
    }
    acc[0]  = fmaf((float)u0[0], c, acc[0]);  acc[1]  = fmaf((float)u0[1], c, acc[1]);
    acc[2]  = fmaf((float)u1[0], c, acc[2]);  acc[3]  = fmaf((float)u1[1], c, acc[3]);
    acc[4]  = fmaf((float)u2[0], c, acc[4]);  acc[5]  = fmaf((float)u2[1], c, acc[5]);
    acc[6]  = fmaf((float)u3[0], c, acc[6]);  acc[7]  = fmaf((float)u3[1], c, acc[7]);
    acc[8]  = fmaf((float)u4[0], c, acc[8]);  acc[9]  = fmaf((float)u4[1], c, acc[9]);
    acc[10] = fmaf((float)u5[0], c, acc[10]); acc[11] = fmaf((float)u5[1], c, acc[11]);
    acc[12] = fmaf((float)u6[0], c, acc[12]); acc[13] = fmaf((float)u6[1], c, acc[13]);
    acc[14] = fmaf((float)u7[0], c, acc[14]); acc[15] = fmaf((float)u7[1], c, acc[15]);
  }
  if constexpr (UNIFORM) {
#pragma unroll
    for (int d = 0; d < D_; ++d) acc[d] *= (1.0f / J_);
  }
  // combine the wave's two i-substreams (lane l <-> l^32, same j)
#pragma unroll
  for (int d = 0; d < D_; ++d) acc[d] += __shfl_xor(acc[d], 32, 64);

  __shared__ float sp[4][J_][D_ + 1];
  if (sub == 0) {
#pragma unroll
    for (int d = 0; d < D_; ++d) sp[wave][j][d] = acc[d];
  }
  __syncthreads();
  float* dst = part + ((size_t)b * NBLK_ + blockIdx.x) * (J_ * D_);
  for (int k = t; k < J_ * D_; k += 256) {
    const int jj = k >> 4, dd = k & 15;
    dst[k] = sp[0][jj][dd] + sp[1][jj][dd] + sp[2][jj][dd] + sp[3][jj][dd];
  }
}

// ---------------------------------------------------------------------------
// K_finish<ADD_PREV, TO_OUT>: s[b][k] = sum_blk part[b][blk][k] (k in 0..511),
// v = squash per j-row (16-lane shfl reduce), then
//   vsum = (ADD_PREV ? vsum : 0) + v   (if !TO_OUT)
//   out  = v                           (if TO_OUT)
// grid = B blocks x 256 threads; thread t owns elements t and t+256.
// ---------------------------------------------------------------------------
template <bool ADD_PREV, bool TO_OUT>
__global__ __launch_bounds__(256) void k_finish(const float* __restrict__ part,
                                                float* __restrict__ vsum,
                                                float* __restrict__ out) {
  const int b = blockIdx.x;
  const int t = threadIdx.x;
  const float* pb = part + (size_t)b * NBLK_ * (J_ * D_);
  float slo = 0.f, shi = 0.f;
#pragma unroll
  for (int blk = 0; blk < NBLK_; ++blk) {
    slo += pb[blk * (J_ * D_) + t];
    shi += pb[blk * (J_ * D_) + t + 256];
  }
  // row-norm: 16 consecutive threads share a j-row
  float nlo = slo * slo, nhi = shi * shi;
#pragma unroll
  for (int off = 8; off > 0; off >>= 1) {
    nlo += __shfl_xor(nlo, off, 16);
    nhi += __shfl_xor(nhi, off, 16);
  }
  nlo += 1e-7f; nhi += 1e-7f;
  const float sclo = nlo / ((1.f + nlo) * sqrtf(nlo));
  const float schi = nhi / ((1.f + nhi) * sqrtf(nhi));
  const float vlo = sclo * slo, vhi = schi * shi;
  if constexpr (TO_OUT) {
    out[(size_t)b * (J_ * D_) + t] = vlo;
    out[(size_t)b * (J_ * D_) + t + 256] = vhi;
  } else {
    float plo = 0.f, phi = 0.f;
    if constexpr (ADD_PREV) {
      plo = vsum[(size_t)b * (J_ * D_) + t];
      phi = vsum[(size_t)b * (J_ * D_) + t + 256];
    }
    vsum[(size_t)b * (J_ * D_) + t] = plo + vlo;
    vsum[(size_t)b * (J_ * D_) + t + 256] = phi + vhi;
  }
}

}  // namespace

extern "C" void kernel_launch(void* const* d_in, const int* in_sizes, int n_in,
                              void* d_out, int out_size, void* d_ws, size_t ws_size,
                              hipStream_t stream) {
  const float* x = (const float*)d_in[0];   // [B, I, P] fp32
  const float* W = (const float*)d_in[1];   // [I, J, D, P] fp32
  float* out = (float*)d_out;               // [B, J, D] fp32

  char* ws = (char*)d_ws;
  uint16_t* uhat = (uint16_t*)ws;                               // 128 MB fp16
  const size_t UHAT_BYTES = (size_t)I_ * B_ * ROWS_ * 2;
  float* part = (float*)(ws + UHAT_BYTES);                      // 2 MB
  float* vsum = part + (size_t)B_ * NBLK_ * (J_ * D_);          // 128 KB

  k_uhat<<<I_, 256, 0, stream>>>(x, W, uhat);

  const dim3 rg(NBLK_, B_);
  k_route<true><<<rg, 256, 0, stream>>>((const uint4*)uhat, nullptr, part);
  k_finish<false, false><<<B_, 256, 0, stream>>>(part, vsum, nullptr);
  k_route<false><<<rg, 256, 0, stream>>>((const uint4*)uhat, vsum, part);
  k_finish<true, false><<<B_, 256, 0, stream>>>(part, vsum, nullptr);
  k_route<false><<<rg, 256, 0, stream>>>((const uint4*)uhat, vsum, part);
  k_finish<false, true><<<B_, 256, 0, stream>>>(part, nullptr, out);
}

// Round 8
// 214.799 us; speedup vs baseline: 1.4076x; 1.2250x over previous
//
#include <hip/hip_runtime.h>
#include <hip/hip_bf16.h>
#include <stdint.h>

// CapsuleLayer dynamic routing, MI355X (gfx950).
// B=64, I=2048, P=16, J=32, D=16, ROUTINGS=3.
// Round 7 (resubmit; prior attempt hit GPU-acquisition timeout, never ran):
// k_uhat stages its 64KB output tile in LDS (XOR-swizzled) and emits
// fully-coalesced 1KB-per-wave stores (kills the 1.45x write amplification /
// scattered-store stalls of rounds 2-6). k_finish folded into route prologue
// (cooperative squash via LDS); memset removed; 8 -> 5 dispatches.

namespace {
constexpr int B_ = 64;
constexpr int I_ = 2048;
constexpr int P_ = 16;
constexpr int J_ = 32;
constexpr int D_ = 16;
constexpr int CI_ = 128;        // i-range per routing block
constexpr int NBLK_ = I_ / CI_; // 16 partial slabs per b
constexpr int ROWS_ = J_ * D_;  // 512 output rows per i

using half8 = __attribute__((ext_vector_type(8))) _Float16;
using h2    = __attribute__((ext_vector_type(2))) _Float16;
using f32x4 = __attribute__((ext_vector_type(4))) float;

__device__ __forceinline__ uint32_t pkh2(float a, float b) {
  union { h2 h; uint32_t u; } z;
  z.h[0] = (_Float16)a; z.h[1] = (_Float16)b;
  return z.u;
}
__device__ __forceinline__ h2 as_h2(uint32_t u) {
  union { uint32_t uu; h2 h; } z; z.uu = u; return z.h;
}
__device__ __forceinline__ float dot2acc(h2 a, h2 b, float c) {
#if __has_builtin(__builtin_amdgcn_fdot2)
  return __builtin_amdgcn_fdot2(a, b, c, false);
#else
  return fmaf((float)a[0], (float)b[0], fmaf((float)a[1], (float)b[1], c));
#endif
}

// ---------------------------------------------------------------------------
// K0: u_hat[i][b][ro] = sum_p x[b,i,p] * W[i,ro,p], fp16.
// One block per i. MFMA 16x16x32 f16 (k 16..31 zero-padded); operand placement
// identical to rounds 4-6 (validated): A = W_i [M=16 ro x K=p], B = x_i^T
// [K=p x N=16 b]; D: col(lane&15)=b-in-tile, row(4*(lane>>4)+reg)=ro-in-tile.
// Results go to LDS (swizzled: half-idx = b*512 + (ro ^ ((b&14)<<2)) -> epilogue
// writes spread over banks, copy reads contiguous), then one coalesced copy
// phase: each wave stores 1024B contiguous dwordx4 per iteration -> every
// 128B line written exactly once, in full, by one instruction.
// ---------------------------------------------------------------------------
__global__ __launch_bounds__(256) void k_uhat(const float* __restrict__ x,
                                              const float* __restrict__ W,
                                              uint16_t* __restrict__ uhat) {
  const int i = blockIdx.x;
  const int t = threadIdx.x;
  const int w = t >> 6;   // wave 0..3
  const int l = t & 63;
  const int g = l >> 4;   // 16-lane group
  const int r16 = l & 15;

  __shared__ uint16_t sbuf[B_ * ROWS_];  // 64 KB staging

  // B-frags: x^T tiles bm=0..3. Lane holds B[k=8g+e, col=b=16bm+r16]; k>=16 -> 0.
  half8 bfr[4];
#pragma unroll
  for (int bm = 0; bm < 4; ++bm) {
    half8 f;
#pragma unroll
    for (int e = 0; e < 8; ++e) f[e] = (_Float16)0.f;
    if (g < 2) {
      const float* bp = x + (size_t)(16 * bm + r16) * (I_ * P_) + (size_t)i * P_ + 8 * g;
      const float4 u0 = *reinterpret_cast<const float4*>(bp);
      const float4 u1 = *reinterpret_cast<const float4*>(bp + 4);
      f[0] = (_Float16)u0.x; f[1] = (_Float16)u0.y; f[2] = (_Float16)u0.z; f[3] = (_Float16)u0.w;
      f[4] = (_Float16)u1.x; f[5] = (_Float16)u1.y; f[6] = (_Float16)u1.z; f[7] = (_Float16)u1.w;
    }
    bfr[bm] = f;
  }

  const float* Wi = W + (size_t)i * (ROWS_ * P_);

#pragma unroll
  for (int nn = 0; nn < 8; ++nn) {
    const int n = 8 * w + nn;  // ro (M) tile
    half8 af;
#pragma unroll
    for (int e = 0; e < 8; ++e) af[e] = (_Float16)0.f;
    if (g < 2) {
      const float* ap = Wi + (size_t)(16 * n + r16) * P_ + 8 * g;
      const float4 u0 = *reinterpret_cast<const float4*>(ap);
      const float4 u1 = *reinterpret_cast<const float4*>(ap + 4);
      af[0] = (_Float16)u0.x; af[1] = (_Float16)u0.y; af[2] = (_Float16)u0.z; af[3] = (_Float16)u0.w;
      af[4] = (_Float16)u1.x; af[5] = (_Float16)u1.y; af[6] = (_Float16)u1.z; af[7] = (_Float16)u1.w;
    }

#pragma unroll
    for (int bm = 0; bm < 4; ++bm) {
      f32x4 acc;
      acc[0] = 0.f; acc[1] = 0.f; acc[2] = 0.f; acc[3] = 0.f;
      acc = __builtin_amdgcn_mfma_f32_16x16x32_f16(af, bfr[bm], acc, 0, 0, 0);
      const int b = 16 * bm + r16;
      const int ro = 16 * n + 4 * g;  // acc[r] -> ro+r
      const int idx = b * ROWS_ + (ro ^ ((b & 14) << 2));  // swizzled, 8B aligned
      uint2 st;
      st.x = pkh2(acc[0], acc[1]);
      st.y = pkh2(acc[2], acc[3]);
      *reinterpret_cast<uint2*>(&sbuf[idx]) = st;
    }
  }

  __syncthreads();

  // Copy phase: wave w handles b = 4k + w; lanes cover ro = l*8..l*8+7.
  // Global store per wave-iter = 64 lanes x 16B = 1024B contiguous.
  uint16_t* out_i = uhat + (size_t)i * (B_ * ROWS_);
#pragma unroll
  for (int k = 0; k < 16; ++k) {
    const int b = 4 * k + w;
    const int ro = l * 8;
    const int c = (b & 14) << 2;  // bits 3-5 only: 8-half blocks map wholesale
    const uint4 v = *reinterpret_cast<const uint4*>(&sbuf[b * ROWS_ + (ro ^ c)]);
    *reinterpret_cast<uint4*>(&out_i[b * ROWS_ + ro]) = v;
  }
}

// ---------------------------------------------------------------------------
// squash-accumulate helper for the cooperative prologue / k_out:
// thread tk owns s-elements k=tk and k=tk+256 of s[b][512]; 16-thread rows
// share a j; shfl(16) row-reduce for the norm.
// ---------------------------------------------------------------------------
__device__ __forceinline__ void accum_squash(const float* __restrict__ pb, int tk,
                                             float& vlo, float& vhi) {
  float slo = 0.f, shi = 0.f;
#pragma unroll
  for (int blk = 0; blk < NBLK_; ++blk) {
    slo += pb[blk * (J_ * D_) + tk];
    shi += pb[blk * (J_ * D_) + tk + 256];
  }
  float nlo = slo * slo, nhi = shi * shi;
#pragma unroll
  for (int off = 8; off > 0; off >>= 1) {
    nlo += __shfl_xor(nlo, off, 16);
    nhi += __shfl_xor(nhi, off, 16);
  }
  nlo += 1e-7f; nhi += 1e-7f;
  vlo += slo * (nlo / ((1.f + nlo) * sqrtf(nlo)));
  vhi += shi * (nhi / ((1.f + nhi) * sqrtf(nhi)));
}

// ---------------------------------------------------------------------------
// K_route<PASS>: one routing pass over fp16 u_hat[i][b][ro].
//   PASS 0: c = 1/32. PASS 1: vsum = squash(s0). PASS 2: squash(s0)+squash(s1),
//   with s_k cooperatively reduced from part slabs in the prologue (fused
//   k_finish): 256 threads sum+squash -> vlds[32][17] f32 -> lanes pack vh[8].
//   Main loop: logit = fdot2(u, vsum); softmax_j over 32 lanes (no max-sub);
//   acc += c*u via mix-FMA. Partials to part_out[b][blk][512], plain stores.
// ---------------------------------------------------------------------------
template <int PASS>
__global__ __launch_bounds__(256) void k_route(const uint4* __restrict__ uhat,
                                               const float* __restrict__ part0,
                                               const float* __restrict__ part1,
                                               float* __restrict__ part_out) {
  const int b = blockIdx.y;
  const int i0 = blockIdx.x * CI_;
  const int t = threadIdx.x;
  const int lane = t & 63;
  const int wave = t >> 6;    // 0..3
  const int sub = lane >> 5;  // i sub-stream
  const int j = lane & 31;

  __shared__ float vlds[J_][D_ + 1];
  h2 vh[8];
  if constexpr (PASS > 0) {
    float vlo = 0.f, vhi = 0.f;
    accum_squash(part0 + (size_t)b * NBLK_ * (J_ * D_), t, vlo, vhi);
    if constexpr (PASS == 2)
      accum_squash(part1 + (size_t)b * NBLK_ * (J_ * D_), t, vlo, vhi);
    vlds[t >> 4][t & 15] = vlo;        // j = t>>4 (0..15)
    vlds[16 + (t >> 4)][t & 15] = vhi; // j = 16..31
    __syncthreads();
#pragma unroll
    for (int q = 0; q < 8; ++q) {
      h2 hv;
      hv[0] = (_Float16)vlds[j][2 * q];
      hv[1] = (_Float16)vlds[j][2 * q + 1];
      vh[q] = hv;
    }
  }

  float acc[D_];
#pragma unroll
  for (int d = 0; d < D_; ++d) acc[d] = 0.f;

  const uint4* up = uhat + ((size_t)(i0 + wave * 2 + sub) * B_ + b) * (ROWS_ / 8) + j * 2;
  const size_t step = (size_t)8 * B_ * (ROWS_ / 8);  // 8 i's per iteration

#pragma unroll 4
  for (int it = 0; it < CI_ / 8; ++it, up += step) {
    const uint4 q0 = up[0], q1 = up[1];  // 16 fp16 = one (i,b,j,:) row
    const h2 u0 = as_h2(q0.x), u1 = as_h2(q0.y), u2 = as_h2(q0.z), u3 = as_h2(q0.w);
    const h2 u4 = as_h2(q1.x), u5 = as_h2(q1.y), u6 = as_h2(q1.z), u7 = as_h2(q1.w);
    float c;
    if constexpr (PASS == 0) {
      c = 1.0f;
    } else {
      float lg = 0.f;
      lg = dot2acc(u0, vh[0], lg); lg = dot2acc(u1, vh[1], lg);
      lg = dot2acc(u2, vh[2], lg); lg = dot2acc(u3, vh[3], lg);
      lg = dot2acc(u4, vh[4], lg); lg = dot2acc(u5, vh[5], lg);
      lg = dot2acc(u6, vh[6], lg); lg = dot2acc(u7, vh[7], lg);
      const float e = __expf(lg);
      float sm = e;
#pragma unroll
      for (int off = 16; off > 0; off >>= 1) sm += __shfl_xor(sm, off, 32);
      c = e * __builtin_amdgcn_rcpf(sm);
    }
    acc[0]  = fmaf((float)u0[0], c, acc[0]);  acc[1]  = fmaf((float)u0[1], c, acc[1]);
    acc[2]  = fmaf((float)u1[0], c, acc[2]);  acc[3]  = fmaf((float)u1[1], c, acc[3]);
    acc[4]  = fmaf((float)u2[0], c, acc[4]);  acc[5]  = fmaf((float)u2[1], c, acc[5]);
    acc[6]  = fmaf((float)u3[0], c, acc[6]);  acc[7]  = fmaf((float)u3[1], c, acc[7]);
    acc[8]  = fmaf((float)u4[0], c, acc[8]);  acc[9]  = fmaf((float)u4[1], c, acc[9]);
    acc[10] = fmaf((float)u5[0], c, acc[10]); acc[11] = fmaf((float)u5[1], c, acc[11]);
    acc[12] = fmaf((float)u6[0], c, acc[12]); acc[13] = fmaf((float)u6[1], c, acc[13]);
    acc[14] = fmaf((float)u7[0], c, acc[14]); acc[15] = fmaf((float)u7[1], c, acc[15]);
  }
  if constexpr (PASS == 0) {
#pragma unroll
    for (int d = 0; d < D_; ++d) acc[d] *= (1.0f / J_);
  }
  // combine the wave's two i-substreams (lane l <-> l^32, same j)
#pragma unroll
  for (int d = 0; d < D_; ++d) acc[d] += __shfl_xor(acc[d], 32, 64);

  __shared__ float sp[4][J_][D_ + 1];
  if (sub == 0) {
#pragma unroll
    for (int d = 0; d < D_; ++d) sp[wave][j][d] = acc[d];
  }
  __syncthreads();
  float* dst = part_out + ((size_t)b * NBLK_ + blockIdx.x) * (J_ * D_);
  for (int k = t; k < J_ * D_; k += 256) {
    const int jj = k >> 4, dd = k & 15;
    dst[k] = sp[0][jj][dd] + sp[1][jj][dd] + sp[2][jj][dd] + sp[3][jj][dd];
  }
}

// ---------------------------------------------------------------------------
// K_out: out[b] = squash(sum_blk part2[b][blk][:]). grid = B x 256.
// ---------------------------------------------------------------------------
__global__ __launch_bounds__(256) void k_out(const float* __restrict__ part2,
                                             float* __restrict__ out) {
  const int b = blockIdx.x;
  const int t = threadIdx.x;
  float vlo = 0.f, vhi = 0.f;
  accum_squash(part2 + (size_t)b * NBLK_ * (J_ * D_), t, vlo, vhi);
  out[(size_t)b * (J_ * D_) + t] = vlo;
  out[(size_t)b * (J_ * D_) + t + 256] = vhi;
}

}  // namespace

extern "C" void kernel_launch(void* const* d_in, const int* in_sizes, int n_in,
                              void* d_out, int out_size, void* d_ws, size_t ws_size,
                              hipStream_t stream) {
  const float* x = (const float*)d_in[0];   // [B, I, P] fp32
  const float* W = (const float*)d_in[1];   // [I, J, D, P] fp32
  float* out = (float*)d_out;               // [B, J, D] fp32

  char* ws = (char*)d_ws;
  uint16_t* uhat = (uint16_t*)ws;                               // 128 MB fp16
  const size_t UHAT_BYTES = (size_t)I_ * B_ * ROWS_ * 2;
  float* part0 = (float*)(ws + UHAT_BYTES);                     // 2 MB each
  float* part1 = part0 + (size_t)B_ * NBLK_ * (J_ * D_);
  float* part2 = part1 + (size_t)B_ * NBLK_ * (J_ * D_);

  k_uhat<<<I_, 256, 0, stream>>>(x, W, uhat);

  const dim3 rg(NBLK_, B_);
  k_route<0><<<rg, 256, 0, stream>>>((const uint4*)uhat, nullptr, nullptr, part0);
  k_route<1><<<rg, 256, 0, stream>>>((const uint4*)uhat, part0, nullptr, part1);
  k_route<2><<<rg, 256, 0, stream>>>((const uint4*)uhat, part0, part1, part2);
  k_out<<<B_, 256, 0, stream>>>(part2, out);
}